// Round 11
// baseline (73.315 us; speedup 1.0000x reference)
//
#include <hip/hip_runtime.h>

#define BATCH   8
#define SHAPE_N 8192
#define SKEL_M  2048

// ws layout (floats):
//   [0, 256):            dir1 per-block partial sums (plain stores)
//   [512, 66048):        dir2 partial mins, [quarter q<4][batch b<8][apt 2048]
//   [66048]:             reduce arrival counter (int), zeroed by cd_prep
//   [66056, 66120):      cd_reduce per-block partials (64 floats)
//   [66176, 197248):     skel converted  (8 batches * 4096 uint4 = 512 KB)
//   [197248, 721536):    shape converted (8 batches * 16384 uint4 = 2 MB)
// Every slot read is written earlier in the same iteration (stream order or
// fence+counter order), so no ws init dependence (re-poison-safe).
#define WS2_OFF 512
#define CNT_OFF 66048
#define RED_OFF 66056
#define SKC_OFF 66176
#define SHC_OFF (66176 + 131072)

// MFMA frag types (gfx950: 32x32x16 bf16 — A/B = 8 bf16 (4 VGPRs), C/D = 16 f32)
typedef short bf16x8 __attribute__((ext_vector_type(8)));
typedef float f32x16 __attribute__((ext_vector_type(16)));
union FragU { bf16x8 v; uint4 u4; };

// round-to-nearest-even f32 -> bf16 (result in low 16 bits)
__device__ __forceinline__ unsigned int f2bf(float a) {
    unsigned int u = __float_as_uint(a);
    return (u + 0x7FFFu + ((u >> 16) & 1u)) >> 16;
}
__device__ __forceinline__ float bf2f(unsigned int h) {
    return __uint_as_float(h << 16);
}
__device__ __forceinline__ unsigned int pack2(unsigned int lo, unsigned int hi) {
    return lo | (hi << 16);
}
// v ~= hi + lo (two bf16), residual ~2^-16 relative
__device__ __forceinline__ void bfsplit(float v, unsigned int& h, unsigned int& l) {
    h = f2bf(v);
    l = f2bf(v - bf2f(h));
}

// Converted A-operand (streamed side) for one b-point, hi/lo scheme identical
// to the verified R1/R5 kernels:
//   k=0..2 c_hi  k=3 rb_hi  k=4..6 c_hi  k=7 rb_lo | k=8..10 c_lo  k=11..15 0
__device__ __forceinline__ void conv_point(float bx, float by, float bz,
                                           uint4& hi, uint4& lo) {
    const float cx = -2.f * bx, cy = -2.f * by, cz = -2.f * bz;
    const float rb = bx * bx + by * by + bz * bz;
    unsigned int chx, clx, chy, cly, chz, clz, rbh, rbl;
    bfsplit(cx, chx, clx); bfsplit(cy, chy, cly); bfsplit(cz, chz, clz);
    bfsplit(rb, rbh, rbl);
    hi = make_uint4(pack2(chx, chy), pack2(chz, rbh),
                    pack2(chx, chy), pack2(chz, rbl));
    lo = make_uint4(pack2(clx, cly), pack2(clz, 0u), 0u, 0u);
}

// ---------------------------------------------------------------------------
// cd_prep: convert every b-side point ONCE into fragment order (group g of
// 32 points: 32 hi-uint4 then 32 lo-uint4 = 1 KB/group). Unchanged from R5.
// Also zeroes cd_reduce's arrival counter (stream-ordered before cd_reduce).
// ---------------------------------------------------------------------------
__global__ __launch_bounds__(256) void cd_prep(
    const float* __restrict__ shape, const float* __restrict__ skel,
    float* __restrict__ ws)
{
    if (blockIdx.x == 0 && threadIdx.x == 0)
        ((int*)ws)[CNT_OFF] = 0;

    const int p = blockIdx.x * 256 + threadIdx.x;      // 0 .. 81919
    const float* q;
    uint4* dst;
    int idx;
    if (p < BATCH * SKEL_M) {                          // skel: stride 3
        const int b = p >> 11; idx = p & (SKEL_M - 1);
        q = skel + (size_t)p * 3;
        dst = (uint4*)(ws + SKC_OFF) + (size_t)b * 4096;
    } else {                                           // shape: stride 6
        const int s = p - BATCH * SKEL_M;
        const int b = s >> 13; idx = s & (SHAPE_N - 1);
        q = shape + (size_t)s * 6;
        dst = (uint4*)(ws + SHC_OFF) + (size_t)b * 16384;
    }
    uint4 hi, lo;
    conv_point(q[0], q[1], q[2], hi, lo);
    const int g = idx >> 5, r = idx & 31;
    dst[g * 64 + r]      = hi;
    dst[g * 64 + 32 + r] = lo;
}

// one MFMA step: fragment af vs all 8 resident a-group frags, fold into rmin
__device__ __forceinline__ void step_min8(const FragU& af, const FragU* bf,
                                          float* rmin)
{
    const f32x16 Z = {0,0,0,0,0,0,0,0,0,0,0,0,0,0,0,0};
#pragma unroll
    for (int j = 0; j < 8; ++j) {
        f32x16 D = __builtin_amdgcn_mfma_f32_32x32x16_bf16(
            af.v, bf[j].v, Z, 0, 0, 0);
        // 8x v_min3 tree into the running min
        const float t0 = fminf(fminf(D[0],  D[1]),  D[2]);
        const float t1 = fminf(fminf(D[3],  D[4]),  D[5]);
        const float t2 = fminf(fminf(D[6],  D[7]),  D[8]);
        const float t3 = fminf(fminf(D[9],  D[10]), D[11]);
        const float t4 = fminf(fminf(D[12], D[13]), D[14]);
        const float u0 = fminf(fminf(t0, t1), t2);
        const float u1 = fminf(fminf(t3, t4), D[15]);
        rmin[j] = fminf(rmin[j], fminf(u0, u1));
    }
}

// ---------------------------------------------------------------------------
// Scan 2048 converted b-points against the block's 256 resident a-points
// (8 MFMA B-frags — each streamed fragment feeds 8 MFMAs, HALVING the
// grid-total streamed volume vs R5's 4-frag blocks: 64 -> 32 MB).
// NO LDS, NO BARRIERS. Same verified 8-deep software pipeline as R5:
// preload 8 fragments into named VGPR slots, steady {use g, load g+8}, drain.
// ---------------------------------------------------------------------------
template <int SA>
__device__ __forceinline__ void cd_scan8(
    const float* __restrict__ Araw,   // 256 a-points, stride SA
    const uint4* __restrict__ Bconv,  // 4096 uint4 = 2048 converted b-points
    float* rmin, float* ra)           // [8] outputs per lane (a-group j)
{
    const int tid = threadIdx.x;
    const int l = tid & 63, wv = tid >> 6;
    const unsigned int one = 0x3F80u;

    // resident B-operand frags: col n = l&31; lane-halves are k 0..7 / 8..15
    FragU bf[8];
#pragma unroll
    for (int j = 0; j < 8; ++j) {
        const float* p = Araw + (size_t)(j * 32 + (l & 31)) * SA;
        const float x = p[0], y = p[1], z = p[2];
        ra[j] = x * x + y * y + z * z;
        unsigned int hx, lx, hy, ly, hz, lz;
        bfsplit(x, hx, lx); bfsplit(y, hy, ly); bfsplit(z, hz, lz);
        if (l < 32)    // k=0..7: (a_hi, 1, a_lo, 1)
            bf[j].u4 = make_uint4(pack2(hx, hy), pack2(hz, one),
                                  pack2(lx, ly), pack2(lz, one));
        else           // k=8..15: (a_hi, 0, 0, 0)
            bf[j].u4 = make_uint4(pack2(hx, hy), pack2(hz, 0u), 0u, 0u);
        rmin[j] = 3.4e38f;
    }

    // wave wv owns b-point groups [wv*16, wv*16+16): 16 KB contiguous
    const char* p0 = (const char*)Bconv + wv * 16384 +
                     (l >> 5) * 512 + (l & 31) * 16;

    FragU f[8];
#pragma unroll
    for (int g = 0; g < 8; ++g)                    // issue 8 loads back-to-back
        f[g].u4 = *(const uint4*)(p0 + g * 1024);
#pragma unroll
    for (int g = 0; g < 8; ++g) {                  // steady state: use g, load g+8
        const FragU cur = f[g];
        f[g].u4 = *(const uint4*)(p0 + (g + 8) * 1024);
        step_min8(cur, bf, rmin);
    }
#pragma unroll
    for (int g = 0; g < 8; ++g)                    // drain
        step_min8(f[g], bf, rmin);

    // lane l and l^32 cover complementary rows (b-points) of the same col
#pragma unroll
    for (int j = 0; j < 8; ++j)
        rmin[j] = fminf(rmin[j], __shfl_xor(rmin[j], 32, 64));
}

// ---------------------------------------------------------------------------
// 512 equal blocks (128 MFMA/wave), 2 blocks/CU, no main-loop LDS/barriers:
//   [0,256):   dir1 — a = shape (256 pts), b = full skel batch (converted).
//              Cross-wave min -> sqrt+block-sum over 256 pts -> ws[bid].
//   [256,512): dir2 — a = skel (256 pts), b = one converted shape quarter.
//              Cross-wave min -> plain stores into this quarter's ws slice
//              (same [quarter][batch][apt] layout as the verified R5 kernel).
// XCD swizzle kept from R8 (free): 512 = 8 x 64 contiguous logical blocks.
// ---------------------------------------------------------------------------
__global__ __launch_bounds__(256, 2) void cd_main(
    const float* __restrict__ shape, const float* __restrict__ skel,
    float* __restrict__ ws)
{
    __shared__ float smin[4][256];
    __shared__ float sra[256];
    __shared__ float s_wsum[4];
    const int tid = threadIdx.x;
    const int l = tid & 63, wv = tid >> 6;
    const int bid = (blockIdx.x & 7) * 64 + (blockIdx.x >> 3);   // XCD swizzle
    float rmin[8], ra[8];

    if (bid < 256) {                   // dir1: 32 blocks/batch
        const int b = bid >> 5, asub = bid & 31;
        cd_scan8<6>(shape + ((size_t)b * SHAPE_N + asub * 256) * 6,
                    (const uint4*)(ws + SKC_OFF) + (size_t)b * 4096,
                    rmin, ra);
    } else {                           // dir2: 32 blocks/batch (8 asub x 4 qtr)
        const int j = bid - 256;
        const int b = j >> 5, rem = j & 31;
        const int asub = rem >> 2, bs = rem & 3;
        cd_scan8<3>(skel + ((size_t)b * SKEL_M + asub * 256) * 3,
                    (const uint4*)(ws + SHC_OFF) + (size_t)b * 16384 + bs * 4096,
                    rmin, ra);
    }

    // combine the 4 waves' partial mins (each saw 1/4 of the b-points)
    if (l < 32) {
#pragma unroll
        for (int j = 0; j < 8; ++j) smin[wv][j * 32 + l] = rmin[j];
        if (wv == 0) {
#pragma unroll
            for (int j = 0; j < 8; ++j) sra[j * 32 + l] = ra[j];
        }
    }
    __syncthreads();

    const float m = fminf(fminf(smin[0][tid], smin[1][tid]),
                          fminf(smin[2][tid], smin[3][tid]));
    if (bid < 256) {
        float d = sqrtf(fmaxf(sra[tid] + m, 0.f));
        for (int o = 32; o; o >>= 1) d += __shfl_down(d, o, 64);
        if (l == 0) s_wsum[wv] = d;
        __syncthreads();
        if (tid == 0)
            ws[bid] = s_wsum[0] + s_wsum[1] + s_wsum[2] + s_wsum[3];
    } else {
        const int j = bid - 256;
        const int b = j >> 5, rem = j & 31;
        const int asub = rem >> 2, bs = rem & 3;
        ws[WS2_OFF + bs * (BATCH * SKEL_M) + b * SKEL_M +
           asub * 256 + tid] = sra[tid] + m;
    }
}

// ---------------------------------------------------------------------------
// Parallel reduce: 64 blocks x 256 threads. Each thread owns one dir2
// a-point, min-folds its 4 quarter partials (coalesced, L2-resident),
// clamp+sqrt, block-sums. Block 0 also adds the 256 dir1 partials.
// Each block writes ONE partial; the last-arriving block (fence + atomic
// counter, zeroed by cd_prep) sums the 64 partials in fixed order -> out[0].
// Deterministic. (Verified passing in R3/R5/R8; only the dir1 fold changed.)
// ---------------------------------------------------------------------------
__global__ __launch_bounds__(256) void cd_reduce(
    float* __restrict__ ws, float* __restrict__ out)
{
    __shared__ float s_wsum[4];
    __shared__ int s_last;
    const int t = threadIdx.x;
    const int bid = blockIdx.x;
    const int l = t & 63, wv = t >> 6;
    const int i = bid * 256 + t;                  // a-point 0..16383

    const float v0 = ws[WS2_OFF + i];
    const float v1 = ws[WS2_OFF + 16384 + i];
    const float v2 = ws[WS2_OFF + 32768 + i];
    const float v3 = ws[WS2_OFF + 49152 + i];
    float s = sqrtf(fmaxf(fminf(fminf(v0, v1), fminf(v2, v3)), 0.f));
    if (bid == 0) s += ws[t];                     // dir1 per-block partials

    for (int o = 32; o; o >>= 1) s += __shfl_down(s, o, 64);
    if (l == 0) s_wsum[wv] = s;
    __syncthreads();
    if (t == 0) {
        ws[RED_OFF + bid] = s_wsum[0] + s_wsum[1] + s_wsum[2] + s_wsum[3];
        __threadfence();                          // release partial
        const int old = atomicAdd((int*)ws + CNT_OFF, 1);
        s_last = (old == 63);
    }
    __syncthreads();
    if (s_last && wv == 0) {
        __threadfence();                          // acquire all partials
        float f = ws[RED_OFF + l];                // 64 partials, fixed order
        for (int o = 32; o; o >>= 1) f += __shfl_down(f, o, 64);
        if (l == 0) out[0] = f * 1e-4f;
    }
}

extern "C" void kernel_launch(void* const* d_in, const int* in_sizes, int n_in,
                              void* d_out, int out_size, void* d_ws, size_t ws_size,
                              hipStream_t stream) {
    const float* shape = (const float*)d_in[0];   // (8, 8192, 6) — use first 3
    const float* skel  = (const float*)d_in[1];   // (8, 2048, 3)
    float* out         = (float*)d_out;           // scalar
    float* ws          = (float*)d_ws;            // >= 721536 floats = 2.82 MB

    cd_prep<<<320, 256, 0, stream>>>(shape, skel, ws);
    cd_main<<<512, 256, 0, stream>>>(shape, skel, ws);
    cd_reduce<<<64, 256, 0, stream>>>(ws, out);
}